// Round 21
// baseline (70.633 us; speedup 1.0000x reference)
//
#include <hip/hip_runtime.h>
#include <hip/hip_fp16.h>

typedef _Float16 half8 __attribute__((ext_vector_type(8)));
typedef _Float16 half2v __attribute__((ext_vector_type(2)));
typedef float f32x16 __attribute__((ext_vector_type(16)));
typedef float f32x4v __attribute__((ext_vector_type(4)));

#define MFMA16(A, B, C) __builtin_amdgcn_mfma_f32_32x32x16_f16((A), (B), (C), 0, 0, 0)

__device__ __forceinline__ f32x16 fzero16() {
  f32x16 z;
#pragma unroll
  for (int i = 0; i < 16; ++i) z[i] = 0.0f;
  return z;
}

__device__ __forceinline__ float max16(float vm, const f32x16& s) {
  const float g1 = fmaxf(fmaxf(s[0], s[1]), s[2]);
  const float g2 = fmaxf(fmaxf(s[3], s[4]), s[5]);
  const float g3 = fmaxf(fmaxf(s[6], s[7]), s[8]);
  const float g4 = fmaxf(fmaxf(s[9], s[10]), s[11]);
  const float g5 = fmaxf(fmaxf(s[12], s[13]), s[14]);
  const float h1 = fmaxf(fmaxf(g1, g2), g3);
  const float h2 = fmaxf(fmaxf(g4, g5), s[15]);
  return fmaxf(fmaxf(vm, h1), h2);
}

// ---------------------------------------------------------------------------
// wprep v3: plain-fp16 weights in MFMA-fragment layout; 40 blocks. (kept)
// ---------------------------------------------------------------------------
__global__ __launch_bounds__(256) void wprep_kernel(
    const float* __restrict__ w1, const float* __restrict__ w2,
    const float* __restrict__ w3,
    _Float16* __restrict__ w1p, _Float16* __restrict__ w2p,
    _Float16* __restrict__ w3p)
{
  const int t = threadIdx.x;
  const int blk = blockIdx.x;
  if (blk < 32) {
    const int cot = blk >> 2, sub = blk & 3;
    for (int e = sub * 2048 + t; e < sub * 2048 + 2048; e += 256) {
      const int j = e & 7, l = (e >> 3) & 63, cs = e >> 9;
      const int lr = l & 31, h = l >> 5;
      const int row = cot * 32 + lr;
      const int col = cs * 16 + 4 * h + (j & 3) + 8 * (j >> 2);
      w3p[((cot * 16 + cs) * 64 + l) * 8 + j] = (_Float16)w3[row * 256 + col];
    }
  } else {
    const int sub = blk - 32;   // 0..7
    for (int e = sub * 1024 + t; e < sub * 1024 + 1024; e += 256) {
      const int j = e & 7, l = (e >> 3) & 63, cs = e >> 9;
      const int lr = l & 31, h = l >> 5;
      const int col = cs * 16 + 4 * h + (j & 3) + 8 * (j >> 2);
      const int idx = (cs * 64 + l) * 8 + j;
      w1p[idx] = (_Float16)w1[lr * 256 + col];
      w2p[idx] = (_Float16)w2[lr * 256 + col];
    }
  }
}

// ---------------------------------------------------------------------------
// FUSED qkv projection v4 — plain fp16 + software pipeline. (r20, kept)
// ---------------------------------------------------------------------------
__global__ __launch_bounds__(256) void qkv_proj_kernel(
    const float* __restrict__ x,
    const _Float16* __restrict__ w1p, const float* __restrict__ b1,
    const _Float16* __restrict__ w2p, const float* __restrict__ b2,
    const _Float16* __restrict__ w3p, const float* __restrict__ b3,
    _Float16* __restrict__ qb, _Float16* __restrict__ kb,
    _Float16* __restrict__ vb)
{
  __shared__ f32x4v red[4][2][4][64];   // [wave][q/k][i4][lane], 32 KB
  const int t = threadIdx.x, w = t >> 6, l = t & 63;
  const int lr = l & 31, h = l >> 5;
  const int b = blockIdx.x >> 7;
  const int nt = blockIdx.x & 127;
  const float* xb = x + (size_t)b * 256 * 4096 + nt * 32 + lr;
  const int cot0 = w * 2, cot1 = w * 2 + 1;

  f32x16 accq = fzero16(), acck = fzero16();
  f32x16 accv0 = fzero16(), accv1 = fzero16();

#define LOADX(CS, XF)                                                          \
  {                                                                            \
    const int c0_ = (CS) * 16 + 4 * h;                                         \
    _Pragma("unroll") for (int j = 0; j < 8; ++j)                              \
      XF[j] = xb[(size_t)(c0_ + (j & 3) + 8 * (j >> 2)) * 4096];               \
  }
#define LOADW3(CS, W0, W1)                                                     \
  {                                                                            \
    W0 = *(const half8*)&w3p[((cot0 * 16 + (CS)) * 64 + l) * 8];               \
    W1 = *(const half8*)&w3p[((cot1 * 16 + (CS)) * 64 + l) * 8];               \
  }
#define STEP(CS, XF, W0, W1)                                                   \
  {                                                                            \
    half8 xh;                                                                  \
    _Pragma("unroll") for (int j = 0; j < 8; ++j) xh[j] = (_Float16)XF[j];     \
    accv0 = MFMA16(xh, W0, accv0);                                             \
    accv1 = MFMA16(xh, W1, accv1);                                             \
    if (((CS) >> 2) == w) {                                                    \
      const half8 w1h = *(const half8*)&w1p[((CS) * 64 + l) * 8];              \
      const half8 w2h = *(const half8*)&w2p[((CS) * 64 + l) * 8];              \
      accq = MFMA16(w1h, xh, accq);                                            \
      acck = MFMA16(w2h, xh, acck);                                            \
    }                                                                          \
  }

  float xfA[8], xfB[8];
  half8 w3A0, w3A1, w3B0, w3B1;
  LOADX(0, xfA)
  LOADW3(0, w3A0, w3A1)
#pragma unroll
  for (int cs = 0; cs < 16; cs += 2) {
    if (cs + 1 < 16) { LOADX(cs + 1, xfB) LOADW3(cs + 1, w3B0, w3B1) }
    STEP(cs, xfA, w3A0, w3A1)
    if (cs + 2 < 16) { LOADX(cs + 2, xfA) LOADW3(cs + 2, w3A0, w3A1) }
    STEP(cs + 1, xfB, w3B0, w3B1)
  }
#undef STEP
#undef LOADW3
#undef LOADX

  const float bv0 = b3[cot0 * 32 + lr];
  const float bv1 = b3[cot1 * 32 + lr];
#pragma unroll
  for (int hfq = 0; hfq < 2; ++hfq) {
    half8 p0, p1;
#pragma unroll
    for (int j = 0; j < 8; ++j) {
      p0[j] = (_Float16)(accv0[8 * hfq + j] + bv0);
      p1[j] = (_Float16)(accv1[8 * hfq + j] + bv1);
    }
    const int ms = nt * 2 + hfq;
    *(half8*)&vb[((((size_t)b * 256 + ms) * 8 + cot0) * 64 + l) * 8] = p0;
    *(half8*)&vb[((((size_t)b * 256 + ms) * 8 + cot1) * 64 + l) * 8] = p1;
  }

#pragma unroll
  for (int i4 = 0; i4 < 4; ++i4) {
    f32x4v q4, k4;
#pragma unroll
    for (int c = 0; c < 4; ++c) { q4[c] = accq[4 * i4 + c]; k4[c] = acck[4 * i4 + c]; }
    red[w][0][i4][l] = q4;
    red[w][1][i4][l] = k4;
  }
  __syncthreads();
  if (w < 2) {
    _Float16* dst = (w == 0) ? qb : kb;
    const float* bias = (w == 0) ? b1 : b2;
    f32x16 tot;
#pragma unroll
    for (int i4 = 0; i4 < 4; ++i4) {
      f32x4v v = red[0][w][i4][l];
      v += red[1][w][i4][l];
      v += red[2][w][i4][l];
      v += red[3][w][i4][l];
#pragma unroll
      for (int c = 0; c < 4; ++c) tot[4 * i4 + c] = v[c];
    }
#pragma unroll
    for (int ds = 0; ds < 2; ++ds) {
      half8 ph;
#pragma unroll
      for (int j = 0; j < 8; ++j) {
        const int d = 16 * ds + 4 * h + (j & 3) + 8 * (j >> 2);
        ph[j] = (_Float16)(tot[8 * ds + j] + bias[d]);
      }
      *(half8*)&dst[((((size_t)b * 128 + nt) * 2 + ds) * 64 + l) * 8] = ph;
    }
  }
}

// ---------------------------------------------------------------------------
// attn v17 = v8 inner loop VERBATIM + fused rowmax scan with DEPTH-2 prefetch
// (named registers, no runtime-indexed arrays). V(0),V(1) loads hoisted above
// the scan. Scan QK chain bitwise-identical to main loop => exact max, P<=1.
// ---------------------------------------------------------------------------
__global__ __launch_bounds__(512, 1) void attn_kernel(
    const _Float16* __restrict__ qb, const _Float16* __restrict__ kb,
    const _Float16* __restrict__ vb,
    const float* __restrict__ x, float* __restrict__ out)
{
  __shared__ __align__(16) _Float16 Plds[2][2][2][8][64][8];  // 64 KB
  __shared__ float Mred[2][4][32];
  __shared__ float Lred[2][4][32];
  const int t = threadIdx.x, w = t >> 6, l = t & 63;
  const int lr = l & 31, h = l >> 5;
  const int bid = blockIdx.x;
  const int xcd = bid & 7;
  const int b = xcd >> 1;
  const int rg = ((bid >> 3) << 1) | (xcd & 1);   // row-group of 64 [0,64)
  const int sw = w >> 2;                           // produced slab
  const int kq = w & 3;                            // produced key-quarter
  const int m0 = kq * 32;                          // scan range start

  const _Float16* kbase = kb + (size_t)b * 131072 + (size_t)l * 8;
  const _Float16* vbase = vb + (size_t)b * 1048576 + (size_t)w * 512 + (size_t)l * 8;

#define KF(kt, ds) (*(const half8*)(kbase + ((size_t)(((kt) * 4 + kq) * 2 + (ds))) * 512))
#define KFM(m, ds) (*(const half8*)(kbase + ((size_t)((m) * 2 + (ds))) * 512))
#define VF(kt, ks) (*(const half8*)(vbase + ((size_t)(((kt) * 8 + (ks)) * 8)) * 512))

  const int rt32q = rg * 2 + sw;
  const _Float16* qp = qb + (((size_t)b * 128 + rt32q) * 2 * 64 + l) * 8;
  const half8 qf0 = *(const half8*)qp;
  const half8 qf1 = *(const half8*)(qp + 512);
  const float LOG2E = 1.44269504088896340736f;

  f32x16 acc0 = fzero16(), acc1 = fzero16();
  float Lacc = 0.f;
  half8 va0[8], va1[8];
  half8 ka0, ka1, kb0_, kb1_;

  // ---- V(0),V(1) issued FIRST: latency hides under the rowmax scan ----
#pragma unroll
  for (int ks = 0; ks < 8; ++ks) va0[ks] = VF(0, ks);
#pragma unroll
  for (int ks = 0; ks < 8; ++ks) va1[ks] = VF(1, ks);

  // ---- fused rowmax: wave (sw,kq) scans m in [32kq, 32kq+32), depth-2 ----
  {
    float vm = -3.0e38f;
    half8 sa0 = KFM(m0, 0),     sa1 = KFM(m0, 1);
    half8 sb0 = KFM(m0 + 1, 0), sb1 = KFM(m0 + 1, 1);
    for (int i = 0; i < 32; i += 2) {
      half8 sc0, sc1, sd0, sd1;
      if (i + 2 < 32) { sc0 = KFM(m0 + i + 2, 0); sc1 = KFM(m0 + i + 2, 1); }
      if (i + 3 < 32) { sd0 = KFM(m0 + i + 3, 0); sd1 = KFM(m0 + i + 3, 1); }
      f32x16 s = fzero16();
      s = MFMA16(sa0, qf0, s);
      s = MFMA16(sa1, qf1, s);
      vm = max16(vm, s);
      f32x16 s2 = fzero16();
      s2 = MFMA16(sb0, qf0, s2);
      s2 = MFMA16(sb1, qf1, s2);
      vm = max16(vm, s2);
      sa0 = sc0; sa1 = sc1; sb0 = sd0; sb1 = sd1;
    }
    vm = fmaxf(vm, __shfl_xor(vm, 32));
    if (l < 32) Mred[sw][kq][lr] = vm;
  }
  __syncthreads();
  const float Mr = fmaxf(fmaxf(Mred[sw][0][lr], Mred[sw][1][lr]),
                         fmaxf(Mred[sw][2][lr], Mred[sw][3][lr]));
  const float nM2 = -Mr * LOG2E;

#define EXPPACK(S, BUF, TI)                                                    \
  {                                                                            \
    float pvv[16];                                                             \
    float ls = 0.f;                                                            \
    _Pragma("unroll") for (int i = 0; i < 16; ++i) {                           \
      pvv[i] = exp2f(fmaf((S)[i], LOG2E, nM2)); ls += pvv[i];                  \
    }                                                                          \
    Lacc += ls;                                                                \
    union { half8 v; half2v h2[4]; } u0, u1;                                   \
    _Pragma("unroll") for (int jj = 0; jj < 4; ++jj) {                         \
      auto a0 = __builtin_amdgcn_cvt_pkrtz(pvv[2 * jj], pvv[2 * jj + 1]);      \
      auto a1 = __builtin_amdgcn_cvt_pkrtz(pvv[8 + 2 * jj], pvv[8 + 2 * jj + 1]); \
      u0.h2[jj] = *(half2v*)&a0;                                               \
      u1.h2[jj] = *(half2v*)&a1;                                               \
    }                                                                          \
    *(half8*)&Plds[BUF][TI][sw][kq * 2 + 0][l][0] = u0.v;                      \
    *(half8*)&Plds[BUF][TI][sw][kq * 2 + 1][l][0] = u1.v;                      \
  }

#define PVC(CB, TI, VA)                                                        \
  {                                                                            \
    __builtin_amdgcn_s_setprio(1);                                             \
    _Pragma("unroll") for (int ks = 0; ks < 8; ++ks) {                         \
      const half8 pb0 = *(const half8*)&Plds[CB][TI][0][ks][l][0];             \
      const half8 pb1 = *(const half8*)&Plds[CB][TI][1][ks][l][0];             \
      acc0 = MFMA16(VA[ks], pb0, acc0);                                        \
      acc1 = MFMA16(VA[ks], pb1, acc1);                                        \
    }                                                                          \
    __builtin_amdgcn_s_setprio(0);                                             \
  }

  // ---- produce tiles 0,1 -> buf0; prefetch K(2),K(3) ----
  {
    const half8 k00 = KF(0, 0), k01 = KF(0, 1);
    f32x16 s = fzero16();
    s = MFMA16(k00, qf0, s);
    s = MFMA16(k01, qf1, s);
    ka0 = KF(2, 0); ka1 = KF(2, 1);
    EXPPACK(s, 0, 0)
  }
  {
    const half8 k10 = KF(1, 0), k11 = KF(1, 1);
    f32x16 s = fzero16();
    s = MFMA16(k10, qf0, s);
    s = MFMA16(k11, qf1, s);
    kb0_ = KF(3, 0); kb1_ = KF(3, 1);
    EXPPACK(s, 0, 1)
  }
  asm volatile("s_waitcnt lgkmcnt(0)" ::: "memory");
  __builtin_amdgcn_s_barrier();
  asm volatile("" ::: "memory");

  // ---- 16 periods of 256 keys, ONE barrier each ----
  for (int P = 0; P < 16; ++P) {
    const int CB = P & 1, PB = CB ^ 1;
    const int p0 = 2 * P + 2, p1 = 2 * P + 3;

    if (p0 < 32) {
      f32x16 s = fzero16();
      s = MFMA16(ka0, qf0, s);
      s = MFMA16(ka1, qf1, s);
      if (p0 + 2 < 32) { ka0 = KF(p0 + 2, 0); ka1 = KF(p0 + 2, 1); }
      EXPPACK(s, PB, 0)
    }
    PVC(CB, 0, va0)
    if (p0 < 32) {
#pragma unroll
      for (int ks = 0; ks < 8; ++ks) va0[ks] = VF(p0, ks);
    }

    if (p1 < 32) {
      f32x16 s = fzero16();
      s = MFMA16(kb0_, qf0, s);
      s = MFMA16(kb1_, qf1, s);
      if (p1 + 2 < 32) { kb0_ = KF(p1 + 2, 0); kb1_ = KF(p1 + 2, 1); }
      EXPPACK(s, PB, 1)
    }
    PVC(CB, 1, va1)
    if (p1 < 32) {
#pragma unroll
      for (int ks = 0; ks < 8; ++ks) va1[ks] = VF(p1, ks);
    }

    asm volatile("s_waitcnt lgkmcnt(0)" ::: "memory");
    __builtin_amdgcn_s_barrier();
    asm volatile("" ::: "memory");
  }
#undef PVC
#undef EXPPACK
#undef KF
#undef KFM
#undef VF

  // ---- L reduce: L[slab][row] = sum over 4 quarters ----
  {
    const float l2 = Lacc + __shfl_xor(Lacc, 32);
    if (l < 32) Lred[sw][kq][lr] = l2;
  }
  __syncthreads();
  const float invL0 = 1.0f / (Lred[0][0][lr] + Lred[0][1][lr] + Lred[0][2][lr] + Lred[0][3][lr]);
  const float invL1 = 1.0f / (Lred[1][0][lr] + Lred[1][1][lr] + Lred[1][2][lr] + Lred[1][3][lr]);

  // ---- epilogue: normalize + residual ----
  const float* xb = x + (size_t)b * 1048576;
  float* ob = out + (size_t)b * 1048576;
  const int nn0 = rg * 64 + lr;
  const int nn1 = rg * 64 + 32 + lr;
#pragma unroll
  for (int reg = 0; reg < 16; ++reg) {
    const int crel = (reg & 3) + 8 * (reg >> 2) + 4 * h;
    const int cout = w * 32 + crel;
    const size_t o0 = (size_t)cout * 4096 + nn0;
    ob[o0] = acc0[reg] * invL0 + xb[o0];
    const size_t o1 = (size_t)cout * 4096 + nn1;
    ob[o1] = acc1[reg] * invL1 + xb[o1];
  }
}

extern "C" void kernel_launch(void* const* d_in, const int* in_sizes, int n_in,
                              void* d_out, int out_size, void* d_ws, size_t ws_size,
                              hipStream_t stream) {
  const float* x  = (const float*)d_in[0];
  const float* w1 = (const float*)d_in[1];
  const float* b1 = (const float*)d_in[2];
  const float* w2 = (const float*)d_in[3];
  const float* b2 = (const float*)d_in[4];
  const float* w3 = (const float*)d_in[5];
  const float* b3 = (const float*)d_in[6];
  float* out = (float*)d_out;

  char* ws = (char*)d_ws;
  _Float16* qb  = (_Float16*)(ws);                               // 1 MB
  _Float16* kb  = (_Float16*)(ws + (1u << 20));                  // 1 MB
  _Float16* vb  = (_Float16*)(ws + (2u << 20));                  // 8 MB
  _Float16* w1p = (_Float16*)(ws + (10u << 20) + (64u << 10));   // 16 KB
  _Float16* w2p = (_Float16*)(ws + (10u << 20) + (96u << 10));   // 16 KB
  _Float16* w3p = (_Float16*)(ws + (10u << 20) + (128u << 10));  // 128 KB

  hipLaunchKernelGGL(wprep_kernel, dim3(40), dim3(256), 0, stream,
                     w1, w2, w3, w1p, w2p, w3p);
  hipLaunchKernelGGL(qkv_proj_kernel, dim3(512), dim3(256), 0, stream,
                     x, w1p, b1, w2p, b2, w3p, b3, qb, kb, vb);
  hipLaunchKernelGGL(attn_kernel, dim3(256), dim3(512), 0, stream,
                     qb, kb, vb, x, out);
}